// Round 1
// baseline (703.103 us; speedup 1.0000x reference)
//
#include <hip/hip_runtime.h>
#include <cstdint>
#include <cstddef>

// Graph U-Net (no pooling), N=8192, D=256, L=3.
// R5: SpMM restructured for L2 residency:
//   (1) XCD-partitioned column chunks: 1-D grid, chunk = (blockIdx.x&7)>>2 so
//       XCDs 0-3 only touch hs columns [0,128), XCDs 4-7 only [128,256).
//       Per-XCD gather footprint 2 MB (was 4 MB) -> fits 4 MB L2 with streams.
//   (2) 32-bit gather addressing (v_lshl_add_u32 + SGPR base, no size_t chain).
//   (3) Unroll 8, split accumulator pairs (8 loads in flight, half dep chain).
// GEMM (MFMA bf16 16x16x32, fragments direct from global) unchanged from R4.

#define GN 8192
#define GD 256
#define CAP 320   // max degree capacity; max observed degree ~175

typedef unsigned int uint32;
using frag_ab = __attribute__((ext_vector_type(8))) short;   // 8 bf16
using frag_cd = __attribute__((ext_vector_type(4))) float;   // 4 fp32

// RNE float -> bf16 bits (values are finite; NaN path not needed)
static __device__ inline unsigned short f2bf(float x) {
    uint32 u = __float_as_uint(x);
    u += 0x7fffu + ((u >> 16) & 1u);
    return (unsigned short)(u >> 16);
}

// ---------------------------------------------------------------------------
// Kernel 1: build adjacency lists + dinv. One block per row.
__global__ __launch_bounds__(256) void k_build(const float* __restrict__ g,
                                               unsigned short* __restrict__ col,
                                               int* __restrict__ cnt,
                                               float* __restrict__ dinv)
{
    __shared__ int s_cnt;
    const int i = blockIdx.x;
    const int tid = threadIdx.x;
    if (tid == 0) s_cnt = 0;
    __syncthreads();
    const float4* grow = (const float4*)(g + (size_t)i * GN);
    unsigned short* crow = col + (size_t)i * CAP;
    for (int j4 = tid; j4 < GN / 4; j4 += 256) {
        float4 v = grow[j4];
        int j = j4 * 4;
        if (v.x != 0.0f) { int p = atomicAdd(&s_cnt, 1); if (p < CAP) crow[p] = (unsigned short)(j + 0); }
        if (v.y != 0.0f) { int p = atomicAdd(&s_cnt, 1); if (p < CAP) crow[p] = (unsigned short)(j + 1); }
        if (v.z != 0.0f) { int p = atomicAdd(&s_cnt, 1); if (p < CAP) crow[p] = (unsigned short)(j + 2); }
        if (v.w != 0.0f) { int p = atomicAdd(&s_cnt, 1); if (p < CAP) crow[p] = (unsigned short)(j + 3); }
    }
    __syncthreads();
    if (tid == 0) {
        int n = s_cnt; if (n > CAP) n = CAP;
        cnt[i] = n;
        dinv[i] = rsqrtf((float)s_cnt + 1.0f);
    }
}

// ---------------------------------------------------------------------------
// Kernel 2: hs_bf = bf16(dinv[:,None] * h)
__global__ __launch_bounds__(256) void k_scale(const float* __restrict__ h,
                                               const float* __restrict__ dinv,
                                               unsigned short* __restrict__ hs_bf)
{
    int idx = blockIdx.x * 256 + threadIdx.x;      // float4 index
    float4 v = ((const float4*)h)[idx];
    int row = idx / (GD / 4);
    float dv = dinv[row];
    ushort4 r;
    r.x = f2bf(v.x * dv); r.y = f2bf(v.y * dv);
    r.z = f2bf(v.z * dv); r.w = f2bf(v.w * dv);
    ((ushort4*)hs_bf)[idx] = r;
}

// ---------------------------------------------------------------------------
// Kernel 2b: generic fp32 -> bf16 convert (weights), n multiple of 1024
__global__ __launch_bounds__(256) void k_f2bf(const float* __restrict__ src,
                                              unsigned short* __restrict__ dst)
{
    int idx = blockIdx.x * 256 + threadIdx.x;      // float4 index
    float4 v = ((const float4*)src)[idx];
    ushort4 r;
    r.x = f2bf(v.x); r.y = f2bf(v.y); r.z = f2bf(v.z); r.w = f2bf(v.w);
    ((ushort4*)dst)[idx] = r;
}

// ---------------------------------------------------------------------------
// Kernel 3: SpMM, bf16 gathers. y_bf[i,:] = bf16(dinv[i]*(hs[i,:] + sum_n hs[n,:]))
// 1-D grid of 4096 blocks; 4 rows/block (one wave each).
// chunk = (blockIdx.x & 7) >> 2: with linear-id round-robin XCD dispatch this
// pins column chunk 0 to one half of the XCDs and chunk 1 to the other, so each
// per-XCD 4 MB L2 holds only a 2 MB gather footprint (+ col/y streams).
// Lane owns one uint (2 bf16); addresses computed in 32-bit.
__global__ __launch_bounds__(256) void k_spmm(const uint32* __restrict__ hsw,
                                              const unsigned short* __restrict__ col,
                                              const int* __restrict__ cnt,
                                              const float* __restrict__ dinv,
                                              uint32* __restrict__ yw)
{
    __shared__ unsigned short s_cols[4][CAP];
    const int tid  = threadIdx.x;
    const int lr   = tid >> 6;          // wave id = local row 0..3
    const int lane = tid & 63;
    const int id   = blockIdx.x;        // 0..4095
    const int xcd7 = id & 7;
    const int chunk = xcd7 >> 2;        // XCDs 0-3 -> cols [0,64); 4-7 -> [64,128)
    const int xi    = (id >> 3) * 4 + (xcd7 & 3);   // 0..2047, bijective per chunk
    const int i     = xi * 4 + lr;
    const uint32 base = (uint32)(chunk * 64 + lane);   // uint col index (row stride 128)
    const int n = cnt[i];
    unsigned short* sc = s_cols[lr];
    for (int t = lane; t < n; t += 64) sc[t] = col[(size_t)i * CAP + t];
    // wave-coherent staging: producer == consumer wave; no barrier.

    float alo0 = 0.f, ahi0 = 0.f, alo1 = 0.f, ahi1 = 0.f;
    int t = 0;
    for (; t + 8 <= n; t += 8) {
        uint32 u[8];
#pragma unroll
        for (int k = 0; k < 8; ++k) {
            uint32 off = (uint32)sc[t + k] * 128u + base;
            u[k] = hsw[off];
        }
#pragma unroll
        for (int k = 0; k < 8; k += 2) {
            alo0 += __uint_as_float(u[k]     << 16);
            ahi0 += __uint_as_float(u[k]     & 0xffff0000u);
            alo1 += __uint_as_float(u[k + 1] << 16);
            ahi1 += __uint_as_float(u[k + 1] & 0xffff0000u);
        }
    }
    for (; t < n; ++t) {
        uint32 u = hsw[(uint32)sc[t] * 128u + base];
        alo0 += __uint_as_float(u << 16);
        ahi0 += __uint_as_float(u & 0xffff0000u);
    }
    uint32 us = hsw[(uint32)i * 128u + base];   // self-loop (+I)
    float alo = alo0 + alo1 + __uint_as_float(us << 16);
    float ahi = ahi0 + ahi1 + __uint_as_float(us & 0xffff0000u);
    const float dv = dinv[i];
    alo *= dv; ahi *= dv;
    yw[(uint32)i * 128u + base] = (uint32)f2bf(alo) | ((uint32)f2bf(ahi) << 16);
}

// ---------------------------------------------------------------------------
// Kernel 4: MFMA bf16 linear layer. C = relu(Y @ W^T + b) with epilogues:
//   h_out  (fp32) : layer output (skip storage / final out slots)
//   hs_out (bf16) : bf16(dinv[m]*(v + skip)) — next SpMM input
//   sum_out(fp32) : v + add_src (final h7 + org_h)
// Y [8192][256] bf16 row-major; W [256][256] bf16 row-major ([out][in] -> B^T,
// K contiguous). Fragments loaded directly from global (16 B per lane), no LDS.
// Layouts (m89/m91-verified): A[m=lane&15][k=quad*8+j]; C/D row=quad*4+reg,
// col=lane&15.
__global__ __launch_bounds__(256) void k_gemm(const unsigned short* __restrict__ Y,
                                              const unsigned short* __restrict__ W,
                                              const float* __restrict__ bias,
                                              const float* __restrict__ dinv,
                                              const float* __restrict__ skip,
                                              float* __restrict__ h_out,
                                              unsigned short* __restrict__ hs_out,
                                              float* __restrict__ sum_out,
                                              const float* __restrict__ add_src)
{
    const int tid  = threadIdx.x;
    const int w    = tid >> 6;         // wave 0..3
    const int lane = tid & 63;
    const int quad = lane >> 4;
    const int l16  = lane & 15;
    const int m0 = blockIdx.x * 64 + w * 16;   // wave's 16 rows
    const int n0 = blockIdx.y * 64;            // block's 64 cols

    frag_cd acc0 = {0.f,0.f,0.f,0.f}, acc1 = {0.f,0.f,0.f,0.f};
    frag_cd acc2 = {0.f,0.f,0.f,0.f}, acc3 = {0.f,0.f,0.f,0.f};

    const size_t abase  = (size_t)(m0 + l16) * GD + quad * 8;
    const size_t bbase0 = (size_t)(n0 +  0 + l16) * GD + quad * 8;
    const size_t bbase1 = (size_t)(n0 + 16 + l16) * GD + quad * 8;
    const size_t bbase2 = (size_t)(n0 + 32 + l16) * GD + quad * 8;
    const size_t bbase3 = (size_t)(n0 + 48 + l16) * GD + quad * 8;

#pragma unroll
    for (int k0 = 0; k0 < GD; k0 += 32) {
        frag_ab a  = *(const frag_ab*)(Y + abase  + k0);
        frag_ab b0 = *(const frag_ab*)(W + bbase0 + k0);
        frag_ab b1 = *(const frag_ab*)(W + bbase1 + k0);
        frag_ab b2 = *(const frag_ab*)(W + bbase2 + k0);
        frag_ab b3 = *(const frag_ab*)(W + bbase3 + k0);
        acc0 = __builtin_amdgcn_mfma_f32_16x16x32_bf16(a, b0, acc0, 0, 0, 0);
        acc1 = __builtin_amdgcn_mfma_f32_16x16x32_bf16(a, b1, acc1, 0, 0, 0);
        acc2 = __builtin_amdgcn_mfma_f32_16x16x32_bf16(a, b2, acc2, 0, 0, 0);
        acc3 = __builtin_amdgcn_mfma_f32_16x16x32_bf16(a, b3, acc3, 0, 0, 0);
    }

    const float bn0 = bias[n0 +  0 + l16];
    const float bn1 = bias[n0 + 16 + l16];
    const float bn2 = bias[n0 + 32 + l16];
    const float bn3 = bias[n0 + 48 + l16];

#pragma unroll
    for (int reg = 0; reg < 4; ++reg) {
        const int m = m0 + quad * 4 + reg;
        const float dv = dinv[m];
        float v[4];
        v[0] = fmaxf(acc0[reg] + bn0, 0.f);
        v[1] = fmaxf(acc1[reg] + bn1, 0.f);
        v[2] = fmaxf(acc2[reg] + bn2, 0.f);
        v[3] = fmaxf(acc3[reg] + bn3, 0.f);
#pragma unroll
        for (int nt = 0; nt < 4; ++nt) {
            const size_t idx = (size_t)m * GD + n0 + nt * 16 + l16;
            const float x = v[nt];
            if (h_out)  h_out[idx] = x;
            if (hs_out) {
                float s = skip ? skip[idx] : 0.f;
                hs_out[idx] = f2bf(dv * (x + s));
            }
            if (sum_out) sum_out[idx] = x + add_src[idx];
        }
    }
}

// ---------------------------------------------------------------------------
extern "C" void kernel_launch(void* const* d_in, const int* in_sizes, int n_in,
                              void* d_out, int out_size, void* d_ws, size_t ws_size,
                              hipStream_t stream)
{
    const float* g  = (const float*)d_in[0];
    const float* h  = (const float*)d_in[1];
    const float* Wd = (const float*)d_in[2];
    const float* bd = (const float*)d_in[3];
    const float* Wb = (const float*)d_in[4];
    const float* bb = (const float*)d_in[5];
    const float* Wu = (const float*)d_in[6];
    const float* bu = (const float*)d_in[7];
    float* out = (float*)d_out;

    char* ws = (char*)d_ws;
    float*          dinv = (float*)ws;                               // 32 KB
    int*            cnt  = (int*)(ws + 32 * 1024);                   // 32 KB
    unsigned short* col  = (unsigned short*)(ws + 64 * 1024);        // 5.24 MB
    size_t off = 64 * 1024 + (size_t)GN * CAP * sizeof(unsigned short);
    off = (off + 255) & ~(size_t)255;
    unsigned short* hs_bf = (unsigned short*)(ws + off); off += (size_t)GN * GD * 2;  // 4 MB
    unsigned short* y_bf  = (unsigned short*)(ws + off); off += (size_t)GN * GD * 2;  // 4 MB
    unsigned short* w_bf  = (unsigned short*)(ws + off); off += (size_t)7 * GD * GD * 2; // 0.9 MB
    off = (off + 255) & ~(size_t)255;
    float* dbuf1 = (float*)(ws + off); off += (size_t)GN * GD * 4;   // 8 MB
    float* dbuf2 = (float*)(ws + off); off += (size_t)GN * GD * 4;   // 8 MB
    float* dbuf3 = (float*)(ws + off); off += (size_t)GN * GD * 4;   // 8 MB
    (void)ws_size; (void)in_sizes; (void)n_in; (void)out_size;

    const size_t ND = (size_t)GN * GD;
    const int WSZ = GD * GD;   // 65536 elements per weight matrix
    dim3 ggrid(GN / 64, GD / 64);

    k_build<<<GN, 256, 0, stream>>>(g, col, cnt, dinv);
    k_scale<<<GN * GD / 4 / 256, 256, 0, stream>>>(h, dinv, hs_bf);
    k_f2bf<<<3 * WSZ / 4 / 256, 256, 0, stream>>>(Wd, w_bf + 0 * (size_t)WSZ);
    k_f2bf<<<1 * WSZ / 4 / 256, 256, 0, stream>>>(Wb, w_bf + 3 * (size_t)WSZ);
    k_f2bf<<<3 * WSZ / 4 / 256, 256, 0, stream>>>(Wu, w_bf + 4 * (size_t)WSZ);

    // down 0..2: h_out -> dbuf, hs_out -> hs_bf (no skip)
    k_spmm<<<4096, 256, 0, stream>>>((const uint32*)hs_bf, col, cnt, dinv, (uint32*)y_bf);
    k_gemm<<<ggrid, 256, 0, stream>>>(y_bf, w_bf + 0 * (size_t)WSZ, bd + 0 * GD, dinv, nullptr, dbuf1, hs_bf, nullptr, nullptr);
    k_spmm<<<4096, 256, 0, stream>>>((const uint32*)hs_bf, col, cnt, dinv, (uint32*)y_bf);
    k_gemm<<<ggrid, 256, 0, stream>>>(y_bf, w_bf + 1 * (size_t)WSZ, bd + 1 * GD, dinv, nullptr, dbuf2, hs_bf, nullptr, nullptr);
    k_spmm<<<4096, 256, 0, stream>>>((const uint32*)hs_bf, col, cnt, dinv, (uint32*)y_bf);
    k_gemm<<<ggrid, 256, 0, stream>>>(y_bf, w_bf + 2 * (size_t)WSZ, bd + 2 * GD, dinv, nullptr, dbuf3, hs_bf, nullptr, nullptr);

    // bottom: hs_out with skip = down_outs[2]
    k_spmm<<<4096, 256, 0, stream>>>((const uint32*)hs_bf, col, cnt, dinv, (uint32*)y_bf);
    k_gemm<<<ggrid, 256, 0, stream>>>(y_bf, w_bf + 3 * (size_t)WSZ, bb, dinv, dbuf3, nullptr, hs_bf, nullptr, nullptr);

    // up 0: out[0] = h5; next hs with skip = down_outs[1]
    k_spmm<<<4096, 256, 0, stream>>>((const uint32*)hs_bf, col, cnt, dinv, (uint32*)y_bf);
    k_gemm<<<ggrid, 256, 0, stream>>>(y_bf, w_bf + 4 * (size_t)WSZ, bu + 0 * GD, dinv, dbuf2, out + 0 * ND, hs_bf, nullptr, nullptr);
    // up 1: out[1] = h6; next hs with skip = down_outs[0]
    k_spmm<<<4096, 256, 0, stream>>>((const uint32*)hs_bf, col, cnt, dinv, (uint32*)y_bf);
    k_gemm<<<ggrid, 256, 0, stream>>>(y_bf, w_bf + 5 * (size_t)WSZ, bu + 1 * GD, dinv, dbuf1, out + 1 * ND, hs_bf, nullptr, nullptr);
    // up 2: out[2] = h7; out[3] = h7 + org_h
    k_spmm<<<4096, 256, 0, stream>>>((const uint32*)hs_bf, col, cnt, dinv, (uint32*)y_bf);
    k_gemm<<<ggrid, 256, 0, stream>>>(y_bf, w_bf + 6 * (size_t)WSZ, bu + 2 * GD, dinv, nullptr, out + 2 * ND, nullptr, out + 3 * ND, h);
}